// Round 9
// baseline (1687.309 us; speedup 1.0000x reference)
//
#include <hip/hip_runtime.h>
#include <cstdint>

#define C_LEN 4096
#define E_DIM 1024
#define NBATCH 4

typedef __attribute__((ext_vector_type(4))) float f32x4;
typedef __attribute__((ext_vector_type(16))) float f32x16;
typedef __attribute__((ext_vector_type(8))) short bf16x8;
typedef __attribute__((ext_vector_type(4))) unsigned short u16x4;

__device__ __forceinline__ unsigned short f2bf(float f) {
  uint32_t u = __builtin_bit_cast(uint32_t, f);
  return (unsigned short)((u + 0x7fffu + ((u >> 16) & 1u)) >> 16);
}

__device__ __forceinline__ void gl_lds16(const void* g, void* l) {
  __builtin_amdgcn_global_load_lds(
      (const __attribute__((address_space(1))) void*)g,
      (__attribute__((address_space(3))) void*)l, 16, 0, 0);
}

#define BAR() __builtin_amdgcn_s_barrier()
#define SB0() __builtin_amdgcn_sched_barrier(0)
#define VMC(n) asm volatile("s_waitcnt vmcnt(" #n ")" ::: "memory")
#define LGKM0() asm volatile("s_waitcnt lgkmcnt(0)" ::: "memory")

// -------- RoPE cos/sin table: [C][E/2] f32 each --------
__global__ __launch_bounds__(256) void rope_table(float* __restrict__ cosT,
                                                  float* __restrict__ sinT) {
  int idx = blockIdx.x * 256 + threadIdx.x;  // over C*E/2
  int pos = idx >> 9;
  int i = idx & 511;
  double inv = exp(((double)(-2 * i) / 1024.0) * 9.210340371976184);
  double a = (double)pos * inv;
  double r = a - 6.283185307179586 * rint(a * 0.15915494309189535);
  float rf = (float)r;
  float s, c;
  __sincosf(rf, &s, &c);
  cosT[idx] = c;
  sinT[idx] = s;
}

// -------- fused f32 -> bf16 convert for x, Wq, Wk, Wv --------
__global__ __launch_bounds__(256) void cvt_all(const float* __restrict__ x,
                                               const float* __restrict__ wq,
                                               const float* __restrict__ wk,
                                               const float* __restrict__ wv,
                                               unsigned short* __restrict__ x_bf,
                                               unsigned short* __restrict__ w_bf) {
  int b = blockIdx.x;
  const float* in;
  unsigned short* out;
  long off;
  if (b < 16384) { in = x; out = x_bf; off = (long)b * 1024; }
  else if (b < 17408) { in = wq; out = w_bf; off = (long)(b - 16384) * 1024; }
  else if (b < 18432) { in = wk; out = w_bf + (1l << 20); off = (long)(b - 17408) * 1024; }
  else { in = wv; out = w_bf + (2l << 20); off = (long)(b - 18432) * 1024; }
  long i = off + threadIdx.x * 4;
  f32x4 v = *(const f32x4*)(in + i);
  u16x4 o = {f2bf(v.x), f2bf(v.y), f2bf(v.z), f2bf(v.w)};
  *(u16x4*)(out + i) = o;
}

// ======== 256x128 BT GEMM, 32x32x16 MFMA, BK=32, 8 waves (4M x 2N), OCC 2 ========
// Triple-buffered LDS (72 KiB). Read-ahead register pipeline: per tile j,
// {stage(j+2) -> vmcnt(3) -> barrier -> readF(j+1) || MFMA(j) -> lgkmcnt(0)}.
// Every wave drains its ds_reads (lgkm0) before each barrier, so stage(j+2)
// (targeting the buffer read 2 tiles ago) is race-free. vmcnt(3) retires
// tile j+1's 3 loads (issued one tile earlier), keeping tile j+2's in flight.
// Wave tile 64x64: 2m x 2n frags of 32x32, 2 k-slabs -> 8 MFMA + 8 ds_read_b128
// per tile. Swizzle: granule ^= (row>>1)&3 (r6/r7-verified, 0 conflicts).
// A frag: row=lane&31, k=(lane>>5)*8+e. C/D: col=lane&31,
// row=(r&3)+8*(r>>2)+4*(lane>>5) [guide-verified m74/m101].
// MODE 0: fused QKV projection (N=3072=[Q|K|V]); RoPE on Q/K, transpose V.
// MODE 2: *1/32 + mask, f32 scores (batch-innermost decode for mask L2 reuse).
// MODE 3: plain f32 out (PV).
template <int MODE>
__global__ __launch_bounds__(512, 4) void gemmT(
    const unsigned short* __restrict__ A, const unsigned short* __restrict__ Bm,
    long sAb, long sBb, long sOb, int nr, int nc, int K, int N,
    unsigned short* __restrict__ oQ, unsigned short* __restrict__ oK,
    unsigned short* __restrict__ oVt, float* __restrict__ oF,
    const float* __restrict__ cosT, const float* __restrict__ sinT,
    const float* __restrict__ mask) {
  __shared__ unsigned short LA[3][256 * 32];  // 3 x 16 KiB
  __shared__ unsigned short LB[3][128 * 32];  // 3 x 8 KiB  (72 KiB)
  const int tid = threadIdx.x;
  const int lane = tid & 63;
  const int wid = tid >> 6;
  const int wm = wid >> 1, wn = wid & 1;  // 4M x 2N
  const int l31 = lane & 31, khalf = lane >> 5;

  // XCD chunk (nwg%8==0) + supertile decode
  const int nwg = gridDim.x;
  const int lid = blockIdx.x;
  const int s = (lid & 7) * (nwg >> 3) + (lid >> 3);
  int bz, rt, ct;
  if (MODE == 2) {
    // batch innermost: 4 consecutive blocks share (rt,ct) -> mask tile L2 reuse
    bz = s & 3;
    const int s4 = s >> 2;
    const int scc = nc >> 2;
    const int sid = s4 >> 4, inner = s4 & 15;
    const int srt = sid / scc, sct = sid - srt * scc;
    rt = srt * 4 + (inner >> 2);
    ct = sct * 4 + (inner & 3);
  } else {
    const int scc = nc >> 2;
    const int per_b_st = (nr >> 2) * scc;
    const int sid = s >> 4, inner = s & 15;
    bz = sid / per_b_st;
    const int r2 = sid - bz * per_b_st;
    const int srt = r2 / scc, sct = r2 - srt * scc;
    rt = srt * 4 + (inner >> 2);
    ct = sct * 4 + (inner & 3);
  }

  const unsigned short* Ag = A + sAb * bz + (long)rt * 256 * K;
  const unsigned short* Bg = Bm + sBb * bz + (long)ct * 128 * K;

  // Staging (3 gl_lds/thread): LDS linear, global col granule inverse-swizzled
  const int g_row0 = tid >> 2;
  const int g_c0 = (((tid & 3) ^ ((g_row0 >> 1) & 3)) << 3);
  const int g_row1 = 128 + g_row0;
  const int g_c1 = (((tid & 3) ^ ((g_row1 >> 1) & 3)) << 3);

  auto stage = [&](int t, int b) {
    const unsigned short* a = Ag + t * 32;
    gl_lds16(a + (long)g_row0 * K + g_c0, &LA[b][tid * 8]);
    gl_lds16(a + (long)g_row1 * K + g_c1, &LA[b][(512 + tid) * 8]);
    gl_lds16(Bg + (long)g_row0 * K + t * 32 + g_c0, &LB[b][tid * 8]);
  };

  f32x16 acc[2][2];
#pragma unroll
  for (int mf = 0; mf < 2; ++mf)
#pragma unroll
    for (int nf = 0; nf < 2; ++nf)
#pragma unroll
      for (int r = 0; r < 16; ++r) acc[mf][nf][r] = 0.f;

  bf16x8 A0[4], B0[4], A1[4], B1[4];

  auto readF = [&](bf16x8* Af, bf16x8* Bf, int b) {
#pragma unroll
    for (int mf = 0; mf < 2; ++mf)
#pragma unroll
      for (int ks = 0; ks < 2; ++ks) {
        int row = wm * 64 + mf * 32 + l31;
        int gc = (ks * 2 + khalf) ^ ((row >> 1) & 3);
        Af[mf * 2 + ks] = *(const bf16x8*)&LA[b][row * 32 + gc * 8];
      }
#pragma unroll
    for (int nf = 0; nf < 2; ++nf)
#pragma unroll
      for (int ks = 0; ks < 2; ++ks) {
        int row = wn * 64 + nf * 32 + l31;
        int gc = (ks * 2 + khalf) ^ ((row >> 1) & 3);
        Bf[nf * 2 + ks] = *(const bf16x8*)&LB[b][row * 32 + gc * 8];
      }
  };
  auto mmall = [&](bf16x8* Af, bf16x8* Bf) {
    __builtin_amdgcn_s_setprio(1);
#pragma unroll
    for (int ks = 0; ks < 2; ++ks)
#pragma unroll
      for (int mf = 0; mf < 2; ++mf)
#pragma unroll
        for (int nf = 0; nf < 2; ++nf)
          acc[mf][nf] = __builtin_amdgcn_mfma_f32_32x32x16_bf16(
              Af[mf * 2 + ks], Bf[nf * 2 + ks], acc[mf][nf], 0, 0, 0);
    __builtin_amdgcn_s_setprio(0);
  };

  const int NT = K >> 5;  // BK=32; all K here give even NT
  int bC = 0, bN = 1, bS = 2;
  stage(0, 0);
  stage(1, 1);
  VMC(3);  // tile 0 landed (tile 1's 3 still in flight)
  BAR(); SB0();
  readF(A0, B0, 0);
  LGKM0();

  for (int j = 0; j < NT; j += 2) {
    // ---- even sub-iter: MFMA set0, read set1 ----
    if (j + 2 < NT) { stage(j + 2, bS); VMC(3); } else VMC(0);
    if (j + 1 < NT) { BAR(); SB0(); readF(A1, B1, bN); }
    mmall(A0, B0);
    LGKM0();
    { int t = bC; bC = bN; bN = bS; bS = t; }
    // ---- odd sub-iter: MFMA set1, read set0 ----
    if (j + 3 < NT) { stage(j + 3, bS); VMC(3); } else VMC(0);
    if (j + 2 < NT) { BAR(); SB0(); readF(A0, B0, bN); }
    mmall(A1, B1);
    LGKM0();
    { int t = bC; bC = bN; bN = bS; bS = t; }
  }

  const int row0 = rt * 256 + wm * 64;
  const int col0 = ct * 128 + wn * 64;
#pragma unroll
  for (int mf = 0; mf < 2; ++mf) {
#pragma unroll
    for (int nf = 0; nf < 2; ++nf) {
#pragma unroll
      for (int r = 0; r < 16; ++r) {
        float v = acc[mf][nf][r];
        int row = row0 + mf * 32 + ((r & 3) + 8 * (r >> 2) + 4 * khalf);
        int col = col0 + nf * 32 + l31;
        if (MODE == 0) {
          float pp = __shfl_xor(v, 1);  // RoPE pair partner (col^1: lane^1)
          int sel = col >> 10;          // 0=Q 1=K 2=V (uniform per 32-col frag)
          int lcol = col & 1023;
          if (sel < 2) {
            int pos = row & (C_LEN - 1);
            int i2 = lcol >> 1;
            float c = cosT[pos * (E_DIM / 2) + i2];
            float sn = sinT[pos * (E_DIM / 2) + i2];
            float rv = v * c + ((lcol & 1) ? pp * sn : -pp * sn);
            unsigned short* o = sel ? oK : oQ;
            o[(long)row * E_DIM + lcol] = f2bf(rv);
          } else {
            int b = row >> 12;
            int cc = row & (C_LEN - 1);
            oVt[(long)b * E_DIM * C_LEN + (long)lcol * C_LEN + cc] = f2bf(v);
          }
        } else if (MODE == 2) {
          float sc = v * 0.03125f + mask[(long)row * C_LEN + col];
          oF[sOb * bz + (long)row * C_LEN + col] = sc;
        } else {
          oF[sOb * bz + (long)row * N + col] = v;
        }
      }
    }
  }
}

// -------- row softmax: normalize f32 weights in place + emit bf16 copy --------
__global__ __launch_bounds__(256) void softmax_rows(float* __restrict__ w,
                                                    unsigned short* __restrict__ pb) {
  long row = blockIdx.x;
  float* p = w + row * C_LEN;
  unsigned short* pbp = pb + row * C_LEN;
  int t = threadIdx.x;
  int wid = t >> 6;
  f32x4 v[4];
  float mx = -3.4e38f;
#pragma unroll
  for (int j = 0; j < 4; ++j) {
    v[j] = __builtin_nontemporal_load((const f32x4*)(p + j * 1024 + t * 4));
    mx = fmaxf(mx, fmaxf(fmaxf(v[j].x, v[j].y), fmaxf(v[j].z, v[j].w)));
  }
#pragma unroll
  for (int o = 1; o < 64; o <<= 1) mx = fmaxf(mx, __shfl_xor(mx, o));
  __shared__ float redm[4];
  if ((t & 63) == 0) redm[wid] = mx;
  __syncthreads();
  mx = fmaxf(fmaxf(redm[0], redm[1]), fmaxf(redm[2], redm[3]));
  float sum = 0.f;
#pragma unroll
  for (int j = 0; j < 4; ++j) {
    v[j].x = __expf(v[j].x - mx);
    v[j].y = __expf(v[j].y - mx);
    v[j].z = __expf(v[j].z - mx);
    v[j].w = __expf(v[j].w - mx);
    sum += v[j].x + v[j].y + v[j].z + v[j].w;
  }
#pragma unroll
  for (int o = 1; o < 64; o <<= 1) sum += __shfl_xor(sum, o);
  __shared__ float reds[4];
  if ((t & 63) == 0) reds[wid] = sum;
  __syncthreads();
  sum = reds[0] + reds[1] + reds[2] + reds[3];
  float inv = 1.0f / sum;
#pragma unroll
  for (int j = 0; j < 4; ++j) {
    v[j].x *= inv;
    v[j].y *= inv;
    v[j].z *= inv;
    v[j].w *= inv;
    __builtin_nontemporal_store(v[j], (f32x4*)(p + j * 1024 + t * 4));
    u16x4 o16 = {f2bf(v[j].x), f2bf(v[j].y), f2bf(v[j].z), f2bf(v[j].w)};
    *(u16x4*)(pbp + j * 1024 + t * 4) = o16;
  }
}

extern "C" void kernel_launch(void* const* d_in, const int* in_sizes, int n_in,
                              void* d_out, int out_size, void* d_ws, size_t ws_size,
                              hipStream_t stream) {
  const float* x = (const float*)d_in[0];
  const float* mask = (const float*)d_in[1];
  const float* Wq = (const float*)d_in[2];
  const float* Wk = (const float*)d_in[3];
  const float* Wv = (const float*)d_in[4];
  float* out = (float*)d_out;                           // [B][C][E]
  float* weights = out + (long)NBATCH * C_LEN * E_DIM;  // [B][C][C]

  char* ws = (char*)d_ws;
  const bool big = ws_size >= (160ull << 20);
  float* cosT = (float*)(ws);
  float* sinT = (float*)(ws + (8l << 20));
  unsigned short* x_bf = (unsigned short*)(ws + (16l << 20));
  unsigned short* W_bf = (unsigned short*)(ws + (48l << 20));  // [3072][1024] = Q|K|V
  unsigned short* Q_bf = (unsigned short*)(ws + (54l << 20));
  unsigned short* K_bf = (unsigned short*)(ws + (86l << 20));
  unsigned short* Vt = (unsigned short*)(ws + (big ? (128l << 20) : (118l << 20)));
  unsigned short* P_bf = (unsigned short*)(ws);

  dim3 blk(256);
  dim3 blk512(512);

  rope_table<<<dim3((C_LEN * (E_DIM / 2)) / 256), blk, 0, stream>>>(cosT, sinT);
  cvt_all<<<dim3(19456), blk, 0, stream>>>(x, Wq, Wk, Wv, x_bf, W_bf);

  // fused QKV projection: 64 rt x 24 ct = 1536 blocks
  gemmT<0><<<dim3(1536), blk512, 0, stream>>>(
      x_bf, W_bf, 0, 0, 0, 64, 24, E_DIM, 3 * E_DIM,
      Q_bf, K_bf, Vt, nullptr, cosT, sinT, nullptr);

  // scores = QK^T/32 + mask -> 16 rt x 32 ct x 4 bz = 2048 blocks
  gemmT<2><<<dim3(2048), blk512, 0, stream>>>(
      Q_bf, K_bf, (long)C_LEN * E_DIM, (long)C_LEN * E_DIM, (long)C_LEN * C_LEN,
      16, 32, E_DIM, C_LEN, nullptr, nullptr, nullptr, weights, nullptr, nullptr, mask);

  if (big) {
    softmax_rows<<<dim3(NBATCH * C_LEN), blk, 0, stream>>>(weights, P_bf);
    // out = P @ V: 16 rt x 8 ct x 4 bz = 512 blocks
    gemmT<3><<<dim3(512), blk512, 0, stream>>>(
        P_bf, Vt, (long)C_LEN * C_LEN, (long)E_DIM * C_LEN, (long)C_LEN * E_DIM,
        16, 8, C_LEN, E_DIM, nullptr, nullptr, nullptr, out, nullptr, nullptr, nullptr);
  } else {
    for (int h = 0; h < 2; ++h) {
      float* wgt = weights + (long)h * 2 * C_LEN * C_LEN;
      softmax_rows<<<dim3(2 * C_LEN), blk, 0, stream>>>(wgt, P_bf);
      gemmT<3><<<dim3(256), blk512, 0, stream>>>(
          P_bf, Vt + (long)h * 2 * E_DIM * C_LEN, (long)C_LEN * C_LEN, (long)E_DIM * C_LEN,
          (long)C_LEN * E_DIM, 16, 8, C_LEN, E_DIM,
          nullptr, nullptr, nullptr, out + (long)h * 2 * C_LEN * E_DIM,
          nullptr, nullptr, nullptr);
    }
  }
}

// Round 10
// 796.875 us; speedup vs baseline: 2.1174x; 2.1174x over previous
//
#include <hip/hip_runtime.h>
#include <cstdint>

#define C_LEN 4096
#define E_DIM 1024
#define NBATCH 4

typedef __attribute__((ext_vector_type(4))) float f32x4;
typedef __attribute__((ext_vector_type(8))) short bf16x8;
typedef __attribute__((ext_vector_type(4))) unsigned short u16x4;

__device__ __forceinline__ unsigned short f2bf(float f) {
  uint32_t u = __builtin_bit_cast(uint32_t, f);
  return (unsigned short)((u + 0x7fffu + ((u >> 16) & 1u)) >> 16);
}

__device__ __forceinline__ void gl_lds16(const void* g, void* l) {
  __builtin_amdgcn_global_load_lds(
      (const __attribute__((address_space(1))) void*)g,
      (__attribute__((address_space(3))) void*)l, 16, 0, 0);
}

// -------- RoPE cos/sin table: [C][E/2] f32 each --------
__global__ __launch_bounds__(256) void rope_table(float* __restrict__ cosT,
                                                  float* __restrict__ sinT) {
  int idx = blockIdx.x * 256 + threadIdx.x;  // over C*E/2
  int pos = idx >> 9;
  int i = idx & 511;
  double inv = exp(((double)(-2 * i) / 1024.0) * 9.210340371976184);
  double a = (double)pos * inv;
  double r = a - 6.283185307179586 * rint(a * 0.15915494309189535);
  float rf = (float)r;
  float s, c;
  __sincosf(rf, &s, &c);
  cosT[idx] = c;
  sinT[idx] = s;
}

// -------- fused f32 -> bf16 convert for x, Wq, Wk, Wv --------
__global__ __launch_bounds__(256) void cvt_all(const float* __restrict__ x,
                                               const float* __restrict__ wq,
                                               const float* __restrict__ wk,
                                               const float* __restrict__ wv,
                                               unsigned short* __restrict__ x_bf,
                                               unsigned short* __restrict__ w_bf) {
  int b = blockIdx.x;
  const float* in;
  unsigned short* out;
  long off;
  if (b < 16384) { in = x; out = x_bf; off = (long)b * 1024; }
  else if (b < 17408) { in = wq; out = w_bf; off = (long)(b - 16384) * 1024; }
  else if (b < 18432) { in = wk; out = w_bf + (1l << 20); off = (long)(b - 17408) * 1024; }
  else { in = wv; out = w_bf + (2l << 20); off = (long)(b - 18432) * 1024; }
  long i = off + threadIdx.x * 4;
  f32x4 v = *(const f32x4*)(in + i);
  u16x4 o = {f2bf(v.x), f2bf(v.y), f2bf(v.z), f2bf(v.w)};
  *(u16x4*)(out + i) = o;
}

// ======== m97-structure GEMM: 128x128 tile, BK=32, 256 thr = 4 waves (2x2) ========
// Single-buffered LDS 16 KiB -> ~3 blocks/CU; plain 2-syncthreads loop; NO inline
// waits / setprio / sched_barrier (m97: compiler emits near-optimal lgkmcnt; the
// cross-block wave overlap at occ-3 hides the stage drain). HW-verified 874-912 TF
// class on this chip. Additive verified pieces: XCD chunk + 4x4 supertile decode,
// conflict-free granule swizzle (granule ^= (row>>1)&3; inverse-swizzled global
// src + linear gl_lds dest), mask-batch-innermost decode for MODE 2.
// A[M][K] bf16 row-major, B[N][K] bf16 row-major (B^T form).
// MODE 0: fused QKV projection (N=3072=[Q|K|V]); RoPE on Q/K, transpose-store V.
// MODE 2: *1/32 + mask, f32 scores. MODE 3: plain f32 out (PV).
template <int MODE>
__global__ __launch_bounds__(256) void gemmM(
    const unsigned short* __restrict__ A, const unsigned short* __restrict__ Bm,
    long sAb, long sBb, long sOb, int nr, int nc, int K, int N,
    unsigned short* __restrict__ oQ, unsigned short* __restrict__ oK,
    unsigned short* __restrict__ oVt, float* __restrict__ oF,
    const float* __restrict__ cosT, const float* __restrict__ sinT,
    const float* __restrict__ mask) {
  __shared__ unsigned short sA[128 * 32];  // 8 KiB
  __shared__ unsigned short sB[128 * 32];  // 8 KiB
  const int tid = threadIdx.x;
  const int lane = tid & 63;
  const int wid = tid >> 6;
  const int wm = wid >> 1, wn = wid & 1;  // 2M x 2N waves, 64x64 each
  const int kgrp = lane >> 4, r16 = lane & 15;

  // XCD chunk (nwg%8==0) + 4x4 supertile decode (nr%4==0, nc%4==0)
  const int nwg = gridDim.x;
  const int lid = blockIdx.x;
  const int s = (lid & 7) * (nwg >> 3) + (lid >> 3);
  int bz, rt, ct;
  if (MODE == 2) {
    // batch innermost: 4 consecutive blocks share (rt,ct) -> mask tile L2 reuse
    bz = s & 3;
    const int s4 = s >> 2;
    const int scc = nc >> 2;
    const int sid = s4 >> 4, inner = s4 & 15;
    const int srt = sid / scc, sct = sid - srt * scc;
    rt = srt * 4 + (inner >> 2);
    ct = sct * 4 + (inner & 3);
  } else {
    const int scc = nc >> 2;
    const int per_b_st = (nr >> 2) * scc;
    const int sid = s >> 4, inner = s & 15;
    bz = sid / per_b_st;
    const int r2 = sid - bz * per_b_st;
    const int srt = r2 / scc, sct = r2 - srt * scc;
    rt = srt * 4 + (inner >> 2);
    ct = sct * 4 + (inner & 3);
  }

  const unsigned short* Ag = A + sAb * bz + (long)rt * 128 * K;
  const unsigned short* Bg = Bm + sBb * bz + (long)ct * 128 * K;

  f32x4 acc[4][4];
#pragma unroll
  for (int m = 0; m < 4; ++m)
#pragma unroll
    for (int n = 0; n < 4; ++n) acc[m][n] = {0.f, 0.f, 0.f, 0.f};

  const int NT = K >> 5;
  for (int t = 0; t < NT; ++t) {
    // stage tile t: 128x32 A + 128x32 B; 512 granules each, 2 per thread per op.
    // LDS dest linear (wave-uniform base + lane*16); global src granule
    // inverse-swizzled by the read involution g ^= (row>>1)&3.
#pragma unroll
    for (int q = 0; q < 2; ++q) {
      int G = q * 256 + tid;
      int r = G >> 2, g = G & 3;
      int gc = ((g ^ ((r >> 1) & 3)) << 3);
      gl_lds16(Ag + (long)r * K + t * 32 + gc, &sA[G * 8]);
    }
#pragma unroll
    for (int q = 0; q < 2; ++q) {
      int G = q * 256 + tid;
      int r = G >> 2, g = G & 3;
      int gc = ((g ^ ((r >> 1) & 3)) << 3);
      gl_lds16(Bg + (long)r * K + t * 32 + gc, &sB[G * 8]);
    }
    __syncthreads();  // drains vmcnt -> staged tile visible

    bf16x8 aF[4], bF[4];
#pragma unroll
    for (int m = 0; m < 4; ++m) {
      int row = wm * 64 + m * 16 + r16;
      aF[m] = *(const bf16x8*)&sA[row * 32 + ((kgrp ^ ((row >> 1) & 3)) << 3)];
    }
#pragma unroll
    for (int n = 0; n < 4; ++n) {
      int row = wn * 64 + n * 16 + r16;
      bF[n] = *(const bf16x8*)&sB[row * 32 + ((kgrp ^ ((row >> 1) & 3)) << 3)];
    }
#pragma unroll
    for (int m = 0; m < 4; ++m)
#pragma unroll
      for (int n = 0; n < 4; ++n)
        acc[m][n] = __builtin_amdgcn_mfma_f32_16x16x32_bf16(aF[m], bF[n], acc[m][n], 0, 0, 0);
    __syncthreads();  // all waves done reading before next stage overwrites
  }

  const int row0 = rt * 128 + wm * 64;
  const int col0 = ct * 128 + wn * 64;
#pragma unroll
  for (int m = 0; m < 4; ++m) {
#pragma unroll
    for (int n = 0; n < 4; ++n) {
#pragma unroll
      for (int r = 0; r < 4; ++r) {
        float v = acc[m][n][r];
        int row = row0 + m * 16 + kgrp * 4 + r;  // C/D: col=lane&15, row=(lane>>4)*4+r
        int col = col0 + n * 16 + r16;
        if (MODE == 0) {
          float pp = __shfl_xor(v, 1);  // RoPE pair partner (col^1, same row/reg)
          int sel = col >> 10;          // 0=Q 1=K 2=V (uniform per 64-col wave slice)
          int lcol = col & 1023;
          if (sel < 2) {
            int pos = row & (C_LEN - 1);
            int i2 = lcol >> 1;
            float c = cosT[pos * (E_DIM / 2) + i2];
            float sn = sinT[pos * (E_DIM / 2) + i2];
            float rv = v * c + ((lcol & 1) ? pp * sn : -pp * sn);
            unsigned short* o = sel ? oK : oQ;
            o[(long)row * E_DIM + lcol] = f2bf(rv);
          } else {
            int b = row >> 12;
            int cc = row & (C_LEN - 1);
            oVt[(long)b * E_DIM * C_LEN + (long)lcol * C_LEN + cc] = f2bf(v);
          }
        } else if (MODE == 2) {
          float sc = v * 0.03125f + mask[(long)row * C_LEN + col];
          oF[sOb * bz + (long)row * C_LEN + col] = sc;
        } else {
          oF[sOb * bz + (long)row * N + col] = v;
        }
      }
    }
  }
}

// -------- row softmax: normalize f32 weights in place + emit bf16 copy --------
__global__ __launch_bounds__(256) void softmax_rows(float* __restrict__ w,
                                                    unsigned short* __restrict__ pb) {
  long row = blockIdx.x;
  float* p = w + row * C_LEN;
  unsigned short* pbp = pb + row * C_LEN;
  int t = threadIdx.x;
  int wid = t >> 6;
  f32x4 v[4];
  float mx = -3.4e38f;
#pragma unroll
  for (int j = 0; j < 4; ++j) {
    v[j] = __builtin_nontemporal_load((const f32x4*)(p + j * 1024 + t * 4));
    mx = fmaxf(mx, fmaxf(fmaxf(v[j].x, v[j].y), fmaxf(v[j].z, v[j].w)));
  }
#pragma unroll
  for (int o = 1; o < 64; o <<= 1) mx = fmaxf(mx, __shfl_xor(mx, o));
  __shared__ float redm[4];
  if ((t & 63) == 0) redm[wid] = mx;
  __syncthreads();
  mx = fmaxf(fmaxf(redm[0], redm[1]), fmaxf(redm[2], redm[3]));
  float sum = 0.f;
#pragma unroll
  for (int j = 0; j < 4; ++j) {
    v[j].x = __expf(v[j].x - mx);
    v[j].y = __expf(v[j].y - mx);
    v[j].z = __expf(v[j].z - mx);
    v[j].w = __expf(v[j].w - mx);
    sum += v[j].x + v[j].y + v[j].z + v[j].w;
  }
#pragma unroll
  for (int o = 1; o < 64; o <<= 1) sum += __shfl_xor(sum, o);
  __shared__ float reds[4];
  if ((t & 63) == 0) reds[wid] = sum;
  __syncthreads();
  sum = reds[0] + reds[1] + reds[2] + reds[3];
  float inv = 1.0f / sum;
#pragma unroll
  for (int j = 0; j < 4; ++j) {
    v[j].x *= inv;
    v[j].y *= inv;
    v[j].z *= inv;
    v[j].w *= inv;
    __builtin_nontemporal_store(v[j], (f32x4*)(p + j * 1024 + t * 4));
    u16x4 o16 = {f2bf(v[j].x), f2bf(v[j].y), f2bf(v[j].z), f2bf(v[j].w)};
    *(u16x4*)(pbp + j * 1024 + t * 4) = o16;
  }
}

extern "C" void kernel_launch(void* const* d_in, const int* in_sizes, int n_in,
                              void* d_out, int out_size, void* d_ws, size_t ws_size,
                              hipStream_t stream) {
  const float* x = (const float*)d_in[0];
  const float* mask = (const float*)d_in[1];
  const float* Wq = (const float*)d_in[2];
  const float* Wk = (const float*)d_in[3];
  const float* Wv = (const float*)d_in[4];
  float* out = (float*)d_out;                           // [B][C][E]
  float* weights = out + (long)NBATCH * C_LEN * E_DIM;  // [B][C][C]

  char* ws = (char*)d_ws;
  const bool big = ws_size >= (160ull << 20);
  float* cosT = (float*)(ws);
  float* sinT = (float*)(ws + (8l << 20));
  unsigned short* x_bf = (unsigned short*)(ws + (16l << 20));
  unsigned short* W_bf = (unsigned short*)(ws + (48l << 20));  // [3072][1024] = Q|K|V
  unsigned short* Q_bf = (unsigned short*)(ws + (54l << 20));
  unsigned short* K_bf = (unsigned short*)(ws + (86l << 20));
  unsigned short* Vt = (unsigned short*)(ws + (big ? (128l << 20) : (118l << 20)));
  unsigned short* P_bf = (unsigned short*)(ws);

  dim3 blk(256);

  rope_table<<<dim3((C_LEN * (E_DIM / 2)) / 256), blk, 0, stream>>>(cosT, sinT);
  cvt_all<<<dim3(19456), blk, 0, stream>>>(x, Wq, Wk, Wv, x_bf, W_bf);

  // fused QKV projection: 128 rt x 24 ct = 3072 blocks
  gemmM<0><<<dim3(3072), blk, 0, stream>>>(
      x_bf, W_bf, 0, 0, 0, 128, 24, E_DIM, 3 * E_DIM,
      Q_bf, K_bf, Vt, nullptr, cosT, sinT, nullptr);

  // scores = QK^T/32 + mask -> 32 rt x 32 ct x 4 bz = 4096 blocks
  gemmM<2><<<dim3(4096), blk, 0, stream>>>(
      Q_bf, K_bf, (long)C_LEN * E_DIM, (long)C_LEN * E_DIM, (long)C_LEN * C_LEN,
      32, 32, E_DIM, C_LEN, nullptr, nullptr, nullptr, weights, nullptr, nullptr, mask);

  if (big) {
    softmax_rows<<<dim3(NBATCH * C_LEN), blk, 0, stream>>>(weights, P_bf);
    // out = P @ V: 32 rt x 8 ct x 4 bz = 1024 blocks
    gemmM<3><<<dim3(1024), blk, 0, stream>>>(
        P_bf, Vt, (long)C_LEN * C_LEN, (long)E_DIM * C_LEN, (long)C_LEN * E_DIM,
        32, 8, C_LEN, E_DIM, nullptr, nullptr, nullptr, out, nullptr, nullptr, nullptr);
  } else {
    for (int h = 0; h < 2; ++h) {
      float* wgt = weights + (long)h * 2 * C_LEN * C_LEN;
      softmax_rows<<<dim3(2 * C_LEN), blk, 0, stream>>>(wgt, P_bf);
      gemmM<3><<<dim3(512), blk, 0, stream>>>(
          P_bf, Vt + (long)h * 2 * E_DIM * C_LEN, (long)C_LEN * C_LEN, (long)E_DIM * C_LEN,
          (long)C_LEN * E_DIM, 32, 8, C_LEN, E_DIM,
          nullptr, nullptr, nullptr, out + (long)h * 2 * C_LEN * E_DIM,
          nullptr, nullptr, nullptr);
    }
  }
}

// Round 11
// 689.946 us; speedup vs baseline: 2.4456x; 1.1550x over previous
//
#include <hip/hip_runtime.h>
#include <cstdint>

#define C_LEN 4096
#define E_DIM 1024
#define NBATCH 4

typedef __attribute__((ext_vector_type(4))) float f32x4;
typedef __attribute__((ext_vector_type(8))) short bf16x8;
typedef __attribute__((ext_vector_type(4))) unsigned short u16x4;

__device__ __forceinline__ unsigned short f2bf(float f) {
  uint32_t u = __builtin_bit_cast(uint32_t, f);
  return (unsigned short)((u + 0x7fffu + ((u >> 16) & 1u)) >> 16);
}

__device__ __forceinline__ void gl_lds16(const void* g, void* l) {
  __builtin_amdgcn_global_load_lds(
      (const __attribute__((address_space(1))) void*)g,
      (__attribute__((address_space(3))) void*)l, 16, 0, 0);
}

#define BAR() __builtin_amdgcn_s_barrier()
#define SB0() __builtin_amdgcn_sched_barrier(0)
#define VMC(n) asm volatile("s_waitcnt vmcnt(" #n ")" ::: "memory")
#define LGKM0() asm volatile("s_waitcnt lgkmcnt(0)" ::: "memory")

// -------- RoPE cos/sin table: [C][E/2] f32 each --------
__global__ __launch_bounds__(256) void rope_table(float* __restrict__ cosT,
                                                  float* __restrict__ sinT) {
  int idx = blockIdx.x * 256 + threadIdx.x;  // over C*E/2
  int pos = idx >> 9;
  int i = idx & 511;
  double inv = exp(((double)(-2 * i) / 1024.0) * 9.210340371976184);
  double a = (double)pos * inv;
  double r = a - 6.283185307179586 * rint(a * 0.15915494309189535);
  float rf = (float)r;
  float s, c;
  __sincosf(rf, &s, &c);
  cosT[idx] = c;
  sinT[idx] = s;
}

// -------- fused f32 -> bf16 convert for x, Wq, Wk, Wv --------
__global__ __launch_bounds__(256) void cvt_all(const float* __restrict__ x,
                                               const float* __restrict__ wq,
                                               const float* __restrict__ wk,
                                               const float* __restrict__ wv,
                                               unsigned short* __restrict__ x_bf,
                                               unsigned short* __restrict__ w_bf) {
  int b = blockIdx.x;
  const float* in;
  unsigned short* out;
  long off;
  if (b < 16384) { in = x; out = x_bf; off = (long)b * 1024; }
  else if (b < 17408) { in = wq; out = w_bf; off = (long)(b - 16384) * 1024; }
  else if (b < 18432) { in = wk; out = w_bf + (1l << 20); off = (long)(b - 17408) * 1024; }
  else { in = wv; out = w_bf + (2l << 20); off = (long)(b - 18432) * 1024; }
  long i = off + threadIdx.x * 4;
  f32x4 v = *(const f32x4*)(in + i);
  u16x4 o = {f2bf(v.x), f2bf(v.y), f2bf(v.z), f2bf(v.w)};
  *(u16x4*)(out + i) = o;
}

// ==== 256x128 BT GEMM, BK=32, 256 thr = 4 waves (2x2), WAVE-TILE 128x64 ====
// Rationale (r4-r10 data + m134 cycle constants): wave 64x64 is LDS-issue-bound
// (8 ds_read_b128 x 12cyc = 96 > 16 MFMA x 4.85 = 78) -> ~650 TF cap seen in
// every prior round. Wave 128x64: 12 reads x 12 = 144 < 32 MFMA x 4.85 = 155
// -> MFMA-dominant. Schedule = r7's proven triple-buffer: one barrier + one
// counted vmcnt per K-tile; single fragment set (no r9-style VGPR blowup).
// acc 128 + frags 48 + addr ~ 210 VGPR @ (256,2) -> 2 blocks/CU (72 KiB LDS).
// Swizzle: granule ^= (row>>1)&3 (verified 0 conflicts); inverse-swizzled
// global src + linear gl_lds dest. XCD chunk + 4x4 supertile decode;
// mask-batch-innermost for MODE 2.
// MODE 0: fused QKV projection (N=3072=[Q|K|V]); RoPE on Q/K, transpose V.
// MODE 2: *1/32 + mask, f32 scores. MODE 3: plain f32 out (PV).
template <int MODE>
__global__ __launch_bounds__(256, 2) void gemmW(
    const unsigned short* __restrict__ A, const unsigned short* __restrict__ Bm,
    long sAb, long sBb, long sOb, int nr, int nc, int K, int N,
    unsigned short* __restrict__ oQ, unsigned short* __restrict__ oK,
    unsigned short* __restrict__ oVt, float* __restrict__ oF,
    const float* __restrict__ cosT, const float* __restrict__ sinT,
    const float* __restrict__ mask) {
  __shared__ unsigned short LA[3][256 * 32];  // 3 x 16 KiB
  __shared__ unsigned short LB[3][128 * 32];  // 3 x 8 KiB  (72 KiB)
  const int tid = threadIdx.x;
  const int lane = tid & 63;
  const int wid = tid >> 6;
  const int wm = wid >> 1, wn = wid & 1;  // 2M x 2N waves, wave-tile 128x64
  const int kgrp = lane >> 4, r16 = lane & 15;

  // XCD chunk (nwg%8==0) + 4x4 supertile decode
  const int nwg = gridDim.x;
  const int lid = blockIdx.x;
  const int s = (lid & 7) * (nwg >> 3) + (lid >> 3);
  int bz, rt, ct;
  if (MODE == 2) {
    // batch innermost: 4 consecutive same-XCD blocks share (rt,ct) mask tile
    bz = s & 3;
    const int s4 = s >> 2;
    const int scc = nc >> 2;
    const int sid = s4 >> 4, inner = s4 & 15;
    const int srt = sid / scc, sct = sid - srt * scc;
    rt = srt * 4 + (inner >> 2);
    ct = sct * 4 + (inner & 3);
  } else {
    const int scc = nc >> 2;
    const int per_b_st = (nr >> 2) * scc;
    const int sid = s >> 4, inner = s & 15;
    bz = sid / per_b_st;
    const int r2 = sid - bz * per_b_st;
    const int srt = r2 / scc, sct = r2 - srt * scc;
    rt = srt * 4 + (inner >> 2);
    ct = sct * 4 + (inner & 3);
  }

  const unsigned short* Ag = A + sAb * bz + (long)rt * 256 * K;
  const unsigned short* Bg = Bm + sBb * bz + (long)ct * 128 * K;

  // stage tile t into buffer b: A 1024 granules (4/thr) + B 512 (2/thr) = 6 gl_lds
  auto stage = [&](int t, int b) {
#pragma unroll
    for (int q = 0; q < 4; ++q) {
      int G = q * 256 + tid;
      int r = G >> 2, g = G & 3;
      int gc = ((g ^ ((r >> 1) & 3)) << 3);
      gl_lds16(Ag + (long)r * K + t * 32 + gc, &LA[b][G * 8]);
    }
#pragma unroll
    for (int q = 0; q < 2; ++q) {
      int G = q * 256 + tid;
      int r = G >> 2, g = G & 3;
      int gc = ((g ^ ((r >> 1) & 3)) << 3);
      gl_lds16(Bg + (long)r * K + t * 32 + gc, &LB[b][G * 8]);
    }
  };

  f32x4 acc[8][4];
#pragma unroll
  for (int m = 0; m < 8; ++m)
#pragma unroll
    for (int n = 0; n < 4; ++n) acc[m][n] = {0.f, 0.f, 0.f, 0.f};

  const int NT = K >> 5;
  int bC = 0, bN = 1, bS = 2;
  stage(0, 0);
  stage(1, 1);
  VMC(6);  // tile 0's 6 loads landed; tile 1's 6 in flight
  BAR(); SB0();

  for (int j = 0; j < NT; ++j) {
    bf16x8 aF[8], bF[4];
#pragma unroll
    for (int m = 0; m < 8; ++m) {
      int row = wm * 128 + m * 16 + r16;
      aF[m] = *(const bf16x8*)&LA[bC][row * 32 + ((kgrp ^ ((row >> 1) & 3)) << 3)];
    }
#pragma unroll
    for (int n = 0; n < 4; ++n) {
      int row = wn * 64 + n * 16 + r16;
      bF[n] = *(const bf16x8*)&LB[bC][row * 32 + ((kgrp ^ ((row >> 1) & 3)) << 3)];
    }
    if (j + 2 < NT) stage(j + 2, bS);  // into buffer read 2 tiles ago (sealed)
    __builtin_amdgcn_s_setprio(1);
#pragma unroll
    for (int m = 0; m < 8; ++m)
#pragma unroll
      for (int n = 0; n < 4; ++n)
        acc[m][n] = __builtin_amdgcn_mfma_f32_16x16x32_bf16(aF[m], bF[n], acc[m][n], 0, 0, 0);
    __builtin_amdgcn_s_setprio(0);
    LGKM0();  // this wave's ds_reads drained before barrier (stage-race safety)
    if (j + 1 < NT) {
      // counted: retire tile j+1's 6 loads; keep tile j+2's 6 in flight
      if (j + 2 < NT) { VMC(6); } else { VMC(0); }
      BAR(); SB0();
    }
    { int t = bC; bC = bN; bN = bS; bS = t; }
  }

  const int row0 = rt * 256 + wm * 128;
  const int col0 = ct * 128 + wn * 64;
#pragma unroll
  for (int m = 0; m < 8; ++m) {
#pragma unroll
    for (int n = 0; n < 4; ++n) {
#pragma unroll
      for (int r = 0; r < 4; ++r) {
        float v = acc[m][n][r];
        int row = row0 + m * 16 + kgrp * 4 + r;  // C/D: col=lane&15, row=(lane>>4)*4+r
        int col = col0 + n * 16 + r16;
        if (MODE == 0) {
          float pp = __shfl_xor(v, 1);  // RoPE pair partner (col^1, same row/reg)
          int sel = col >> 10;          // 0=Q 1=K 2=V (uniform per 64-col wave slice)
          int lcol = col & 1023;
          if (sel < 2) {
            int pos = row & (C_LEN - 1);
            int i2 = lcol >> 1;
            float c = cosT[pos * (E_DIM / 2) + i2];
            float sn = sinT[pos * (E_DIM / 2) + i2];
            float rv = v * c + ((lcol & 1) ? pp * sn : -pp * sn);
            unsigned short* o = sel ? oK : oQ;
            o[(long)row * E_DIM + lcol] = f2bf(rv);
          } else {
            int b = row >> 12;
            int cc = row & (C_LEN - 1);
            oVt[(long)b * E_DIM * C_LEN + (long)lcol * C_LEN + cc] = f2bf(v);
          }
        } else if (MODE == 2) {
          float sc = v * 0.03125f + mask[(long)row * C_LEN + col];
          oF[sOb * bz + (long)row * C_LEN + col] = sc;
        } else {
          oF[sOb * bz + (long)row * N + col] = v;
        }
      }
    }
  }
}

// -------- row softmax: normalize f32 weights in place + emit bf16 copy --------
__global__ __launch_bounds__(256) void softmax_rows(float* __restrict__ w,
                                                    unsigned short* __restrict__ pb) {
  long row = blockIdx.x;
  float* p = w + row * C_LEN;
  unsigned short* pbp = pb + row * C_LEN;
  int t = threadIdx.x;
  int wid = t >> 6;
  f32x4 v[4];
  float mx = -3.4e38f;
#pragma unroll
  for (int j = 0; j < 4; ++j) {
    v[j] = __builtin_nontemporal_load((const f32x4*)(p + j * 1024 + t * 4));
    mx = fmaxf(mx, fmaxf(fmaxf(v[j].x, v[j].y), fmaxf(v[j].z, v[j].w)));
  }
#pragma unroll
  for (int o = 1; o < 64; o <<= 1) mx = fmaxf(mx, __shfl_xor(mx, o));
  __shared__ float redm[4];
  if ((t & 63) == 0) redm[wid] = mx;
  __syncthreads();
  mx = fmaxf(fmaxf(redm[0], redm[1]), fmaxf(redm[2], redm[3]));
  float sum = 0.f;
#pragma unroll
  for (int j = 0; j < 4; ++j) {
    v[j].x = __expf(v[j].x - mx);
    v[j].y = __expf(v[j].y - mx);
    v[j].z = __expf(v[j].z - mx);
    v[j].w = __expf(v[j].w - mx);
    sum += v[j].x + v[j].y + v[j].z + v[j].w;
  }
#pragma unroll
  for (int o = 1; o < 64; o <<= 1) sum += __shfl_xor(sum, o);
  __shared__ float reds[4];
  if ((t & 63) == 0) reds[wid] = sum;
  __syncthreads();
  sum = reds[0] + reds[1] + reds[2] + reds[3];
  float inv = 1.0f / sum;
#pragma unroll
  for (int j = 0; j < 4; ++j) {
    v[j].x *= inv;
    v[j].y *= inv;
    v[j].z *= inv;
    v[j].w *= inv;
    __builtin_nontemporal_store(v[j], (f32x4*)(p + j * 1024 + t * 4));
    u16x4 o16 = {f2bf(v[j].x), f2bf(v[j].y), f2bf(v[j].z), f2bf(v[j].w)};
    *(u16x4*)(pbp + j * 1024 + t * 4) = o16;
  }
}

extern "C" void kernel_launch(void* const* d_in, const int* in_sizes, int n_in,
                              void* d_out, int out_size, void* d_ws, size_t ws_size,
                              hipStream_t stream) {
  const float* x = (const float*)d_in[0];
  const float* mask = (const float*)d_in[1];
  const float* Wq = (const float*)d_in[2];
  const float* Wk = (const float*)d_in[3];
  const float* Wv = (const float*)d_in[4];
  float* out = (float*)d_out;                           // [B][C][E]
  float* weights = out + (long)NBATCH * C_LEN * E_DIM;  // [B][C][C]

  char* ws = (char*)d_ws;
  const bool big = ws_size >= (160ull << 20);
  float* cosT = (float*)(ws);
  float* sinT = (float*)(ws + (8l << 20));
  unsigned short* x_bf = (unsigned short*)(ws + (16l << 20));
  unsigned short* W_bf = (unsigned short*)(ws + (48l << 20));  // [3072][1024] = Q|K|V
  unsigned short* Q_bf = (unsigned short*)(ws + (54l << 20));
  unsigned short* K_bf = (unsigned short*)(ws + (86l << 20));
  unsigned short* Vt = (unsigned short*)(ws + (big ? (128l << 20) : (118l << 20)));
  unsigned short* P_bf = (unsigned short*)(ws);

  dim3 blk(256);

  rope_table<<<dim3((C_LEN * (E_DIM / 2)) / 256), blk, 0, stream>>>(cosT, sinT);
  cvt_all<<<dim3(19456), blk, 0, stream>>>(x, Wq, Wk, Wv, x_bf, W_bf);

  // fused QKV projection: 64 rt x 24 ct = 1536 blocks
  gemmW<0><<<dim3(1536), blk, 0, stream>>>(
      x_bf, W_bf, 0, 0, 0, 64, 24, E_DIM, 3 * E_DIM,
      Q_bf, K_bf, Vt, nullptr, cosT, sinT, nullptr);

  // scores = QK^T/32 + mask -> 16 rt x 32 ct x 4 bz = 2048 blocks
  gemmW<2><<<dim3(2048), blk, 0, stream>>>(
      Q_bf, K_bf, (long)C_LEN * E_DIM, (long)C_LEN * E_DIM, (long)C_LEN * C_LEN,
      16, 32, E_DIM, C_LEN, nullptr, nullptr, nullptr, weights, nullptr, nullptr, mask);

  if (big) {
    softmax_rows<<<dim3(NBATCH * C_LEN), blk, 0, stream>>>(weights, P_bf);
    // out = P @ V: 16 rt x 8 ct x 4 bz = 512 blocks
    gemmW<3><<<dim3(512), blk, 0, stream>>>(
        P_bf, Vt, (long)C_LEN * C_LEN, (long)E_DIM * C_LEN, (long)C_LEN * E_DIM,
        16, 8, C_LEN, E_DIM, nullptr, nullptr, nullptr, out, nullptr, nullptr, nullptr);
  } else {
    for (int h = 0; h < 2; ++h) {
      float* wgt = weights + (long)h * 2 * C_LEN * C_LEN;
      softmax_rows<<<dim3(2 * C_LEN), blk, 0, stream>>>(wgt, P_bf);
      gemmW<3><<<dim3(256), blk, 0, stream>>>(
          P_bf, Vt + (long)h * 2 * E_DIM * C_LEN, (long)C_LEN * C_LEN, (long)E_DIM * C_LEN,
          (long)C_LEN * E_DIM, 16, 8, C_LEN, E_DIM,
          nullptr, nullptr, nullptr, out + (long)h * 2 * C_LEN * E_DIM,
          nullptr, nullptr, nullptr);
    }
  }
}

// Round 12
// 616.488 us; speedup vs baseline: 2.7370x; 1.1192x over previous
//
#include <hip/hip_runtime.h>
#include <cstdint>

#define C_LEN 4096
#define E_DIM 1024
#define NBATCH 4

typedef __attribute__((ext_vector_type(4))) float f32x4;
typedef __attribute__((ext_vector_type(8))) short bf16x8;
typedef __attribute__((ext_vector_type(4))) unsigned short u16x4;

__device__ __forceinline__ unsigned short f2bf(float f) {
  uint32_t u = __builtin_bit_cast(uint32_t, f);
  return (unsigned short)((u + 0x7fffu + ((u >> 16) & 1u)) >> 16);
}

__device__ __forceinline__ void gl_lds16(const void* g, void* l) {
  __builtin_amdgcn_global_load_lds(
      (const __attribute__((address_space(1))) void*)g,
      (__attribute__((address_space(3))) void*)l, 16, 0, 0);
}

#define BAR() __builtin_amdgcn_s_barrier()
#define LGKM0() do { asm volatile("s_waitcnt lgkmcnt(0)" ::: "memory"); \
                     __builtin_amdgcn_sched_barrier(0); } while (0)
#define VMC(n) asm volatile("s_waitcnt vmcnt(" #n ")" ::: "memory")

// -------- RoPE cos/sin table: [C][E/2] f32 each --------
__global__ __launch_bounds__(256) void rope_table(float* __restrict__ cosT,
                                                  float* __restrict__ sinT) {
  int idx = blockIdx.x * 256 + threadIdx.x;  // over C*E/2
  int pos = idx >> 9;
  int i = idx & 511;
  double inv = exp(((double)(-2 * i) / 1024.0) * 9.210340371976184);
  double a = (double)pos * inv;
  double r = a - 6.283185307179586 * rint(a * 0.15915494309189535);
  float rf = (float)r;
  float s, c;
  __sincosf(rf, &s, &c);
  cosT[idx] = c;
  sinT[idx] = s;
}

// -------- fused f32 -> bf16 convert for x, Wq, Wk, Wv --------
__global__ __launch_bounds__(256) void cvt_all(const float* __restrict__ x,
                                               const float* __restrict__ wq,
                                               const float* __restrict__ wk,
                                               const float* __restrict__ wv,
                                               unsigned short* __restrict__ x_bf,
                                               unsigned short* __restrict__ w_bf) {
  int b = blockIdx.x;
  const float* in;
  unsigned short* out;
  long off;
  if (b < 16384) { in = x; out = x_bf; off = (long)b * 1024; }
  else if (b < 17408) { in = wq; out = w_bf; off = (long)(b - 16384) * 1024; }
  else if (b < 18432) { in = wk; out = w_bf + (1l << 20); off = (long)(b - 17408) * 1024; }
  else { in = wv; out = w_bf + (2l << 20); off = (long)(b - 18432) * 1024; }
  long i = off + threadIdx.x * 4;
  f32x4 v = *(const f32x4*)(in + i);
  u16x4 o = {f2bf(v.x), f2bf(v.y), f2bf(v.z), f2bf(v.w)};
  *(u16x4*)(out + i) = o;
}

// ======== 256x256 8-phase GEMM (r8 structure, best measured), BK=64 ========
// 512 threads = 8 waves (2M x 4N). LDS 128 KiB [buf(2)][A/B][half][128][64].
// Phase = {ds-reads || stage 1 half-tile -> barrier -> lgkm0 -> setprio MFMA
// -> barrier}; stage slots ph1..8 each land after their buffer-half's seal
// barrier; vmcnt(4) only at ph4/ph8. Swizzle: granule ^= row&7 (0 conflicts),
// inverse-permuted global src + linear gl_lds dest. XCD chunk + 4x4 supertile;
// MODE 2 adds batch-innermost decode (4 same-XCD blocks share the mask tile).
// MODE 0: fused QKV projection (N=3072=[Q|K|V]); RoPE on Q/K, transpose V.
// MODE 2: *1/32 + mask, f32 scores. MODE 3: plain f32 out (PV).
template <int MODE>
__global__ __launch_bounds__(512, 1) void gemm8(
    const unsigned short* __restrict__ A, const unsigned short* __restrict__ Bm,
    long sAb, long sBb, long sOb, int nr, int nc, int K, int N,
    unsigned short* __restrict__ oQ, unsigned short* __restrict__ oK,
    unsigned short* __restrict__ oVt, float* __restrict__ oF,
    const float* __restrict__ cosT, const float* __restrict__ sinT,
    const float* __restrict__ mask) {
  __shared__ unsigned short lds[2][2][2][128 * 64];  // 128 KiB
  const int tid = threadIdx.x;
  const int lane = tid & 63;
  const int wid = tid >> 6;
  const int wm = wid >> 2, wn = wid & 3;  // 2M x 4N
  const int kgrp = lane >> 4, r16 = lane & 15;

  // XCD chunk (nwg%8==0) + 4x4 supertile decode (nr%4==0, nc%4==0)
  const int nwg = gridDim.x;
  const int lid = blockIdx.x;
  const int s = (lid & 7) * (nwg >> 3) + (lid >> 3);
  int bz, rt, ct;
  if (MODE == 2) {
    // batch innermost: 4 consecutive same-XCD blocks share (rt,ct) mask tile
    bz = s & 3;
    const int s4 = s >> 2;
    const int scc = nc >> 2;
    const int sid = s4 >> 4, inner = s4 & 15;
    const int srt = sid / scc, sct = sid - srt * scc;
    rt = srt * 4 + (inner >> 2);
    ct = sct * 4 + (inner & 3);
  } else {
    const int scc = nc >> 2;
    const int per_b_st = (nr >> 2) * scc;
    const int sid = s >> 4, inner = s & 15;
    bz = sid / per_b_st;
    const int r2 = sid - bz * per_b_st;
    const int srt = r2 / scc, sct = r2 - srt * scc;
    rt = srt * 4 + (inner >> 2);
    ct = sct * 4 + (inner & 3);
  }

  const unsigned short* Ag = A + sAb * bz + (long)rt * 256 * K;
  const unsigned short* Bg = Bm + sBb * bz + (long)ct * 256 * K;

  // stage one half-tile (128x64) = 2 gl_lds/thread; LDS linear, src col
  // granule inverse-swizzled by the read involution (g ^= row&7).
  auto stA = [&](int buf, int half, int t) {
#pragma unroll
    for (int q = 0; q < 2; ++q) {
      int G = q * 512 + tid;
      int r = G >> 3, g = G & 7;
      gl_lds16(Ag + (long)(half * 128 + r) * K + t * 64 + ((g ^ (r & 7)) << 3),
               &lds[buf][0][half][G * 8]);
    }
  };
  auto stB = [&](int buf, int half, int t) {
#pragma unroll
    for (int q = 0; q < 2; ++q) {
      int G = q * 512 + tid;
      int r = G >> 3, g = G & 7;
      gl_lds16(Bg + (long)(half * 128 + r) * K + t * 64 + ((g ^ (r & 7)) << 3),
               &lds[buf][1][half][G * 8]);
    }
  };

  f32x4 acc[8][4];
#pragma unroll
  for (int m = 0; m < 8; ++m)
#pragma unroll
    for (int n = 0; n < 4; ++n) acc[m][n] = {0.f, 0.f, 0.f, 0.f};

  bf16x8 aF[8], bF0[4], bF1[4];
  auto rdA = [&](int buf, int mh) {
#pragma unroll
    for (int m = 0; m < 4; ++m) {
      int row = mh * 64 + m * 16 + r16;
#pragma unroll
      for (int ks = 0; ks < 2; ++ks)
        aF[m * 2 + ks] = *(const bf16x8*)&lds[buf][0][wm]
            [row * 64 + ((((ks << 2) + kgrp) ^ (row & 7)) << 3)];
    }
  };
  auto rdB = [&](int buf, int nh, bf16x8* d) {
#pragma unroll
    for (int n = 0; n < 2; ++n) {
      int row = (wn & 1) * 64 + nh * 32 + n * 16 + r16;
#pragma unroll
      for (int ks = 0; ks < 2; ++ks)
        d[n * 2 + ks] = *(const bf16x8*)&lds[buf][1][wn >> 1]
            [row * 64 + ((((ks << 2) + kgrp) ^ (row & 7)) << 3)];
    }
  };
  auto mm = [&](bf16x8* bf, int mh, int nh) {
    __builtin_amdgcn_s_setprio(1);
#pragma unroll
    for (int ks = 0; ks < 2; ++ks)
#pragma unroll
      for (int m = 0; m < 4; ++m)
#pragma unroll
        for (int n = 0; n < 2; ++n)
          acc[mh * 4 + m][nh * 2 + n] = __builtin_amdgcn_mfma_f32_16x16x32_bf16(
              aF[m * 2 + ks], bf[n * 2 + ks], acc[mh * 4 + m][nh * 2 + n], 0, 0, 0);
    __builtin_amdgcn_s_setprio(0);
  };

  const int NIT = K >> 7;  // 2 K-tiles (BK=64) per iteration
  // Prologue: tiles 0 (buf0) and 1 (buf1) fully staged; retire tile 0's 8 loads.
  stA(0, 0, 0); stA(0, 1, 0); stB(0, 0, 0); stB(0, 1, 0);
  stA(1, 0, 1); stA(1, 1, 1); stB(1, 0, 1); stB(1, 1, 1);
  VMC(8);
  BAR();
  __builtin_amdgcn_sched_barrier(0);

  for (int it = 0; it < NIT; ++it) {
    const int t1 = 2 * it + 1, t2 = 2 * it + 2, t3 = 2 * it + 3;
    const bool more = (it + 1 < NIT);
    // ---- ph1: t0 (mh0,nh0) ---- buf1-A sealed at prev ph7
    rdA(0, 0); rdB(0, 0, bF0);
    if (it > 0) stA(1, 0, t1);
    BAR(); LGKM0();
    mm(bF0, 0, 0);
    BAR();
    // ---- ph2: t0 (mh0,nh1) ----
    rdB(0, 1, bF1);
    if (it > 0) stA(1, 1, t1);
    BAR(); LGKM0();
    mm(bF1, 0, 1);
    BAR();
    // ---- ph3: t0 (mh1,nh1) ---- buf0-B sealed at ph2 end
    rdA(0, 1);
    if (more) stB(0, 0, t2);
    BAR(); LGKM0();
    mm(bF1, 1, 1);
    BAR();
    // ---- ph4: t0 (mh1,nh0) ---- vmcnt: tile t1 fully landed for ph5
    if (more) stB(0, 1, t2);
    BAR();
    mm(bF0, 1, 0);
    if (more) { VMC(4); } else { VMC(0); }
    BAR();
    // ---- ph5: t1 (mh0,nh0) ---- buf0-A sealed at ph3 end
    rdA(1, 0); rdB(1, 0, bF0);
    if (more) stA(0, 0, t2);
    BAR(); LGKM0();
    mm(bF0, 0, 0);
    BAR();
    // ---- ph6: t1 (mh0,nh1) ----
    rdB(1, 1, bF1);
    if (more) stA(0, 1, t2);
    BAR(); LGKM0();
    mm(bF1, 0, 1);
    BAR();
    // ---- ph7: t1 (mh1,nh1) ---- buf1-B sealed at ph6 end
    rdA(1, 1);
    if (more) stB(1, 0, t3);
    BAR(); LGKM0();
    mm(bF1, 1, 1);
    BAR();
    // ---- ph8: t1 (mh1,nh0) ---- vmcnt: tile t2 fully landed for next ph1
    if (more) stB(1, 1, t3);
    BAR();
    mm(bF0, 1, 0);
    if (more) { VMC(4); BAR(); }
  }

  const int row0 = rt * 256 + wm * 128;
  const int col0 = ct * 256 + wn * 64;
#pragma unroll
  for (int m = 0; m < 8; ++m) {
#pragma unroll
    for (int n = 0; n < 4; ++n) {
#pragma unroll
      for (int r = 0; r < 4; ++r) {
        float v = acc[m][n][r];
        int row = row0 + m * 16 + kgrp * 4 + r;  // C/D: col=lane&15, row=(lane>>4)*4+r
        int col = col0 + n * 16 + r16;
        if (MODE == 0) {
          float pp = __shfl_xor(v, 1);  // RoPE pair partner (col^1, same row/reg)
          int sel = col >> 10;          // 0=Q 1=K 2=V (uniform per 64-col wave slice)
          int lcol = col & 1023;
          if (sel < 2) {
            int pos = row & (C_LEN - 1);
            int i2 = lcol >> 1;
            float c = cosT[pos * (E_DIM / 2) + i2];
            float sn = sinT[pos * (E_DIM / 2) + i2];
            float rv = v * c + ((lcol & 1) ? pp * sn : -pp * sn);
            unsigned short* o = sel ? oK : oQ;
            o[(long)row * E_DIM + lcol] = f2bf(rv);
          } else {
            int b = row >> 12;
            int cc = row & (C_LEN - 1);
            oVt[(long)b * E_DIM * C_LEN + (long)lcol * C_LEN + cc] = f2bf(v);
          }
        } else if (MODE == 2) {
          float sc = v * 0.03125f + mask[(long)row * C_LEN + col];
          oF[sOb * bz + (long)row * C_LEN + col] = sc;
        } else {
          oF[sOb * bz + (long)row * N + col] = v;
        }
      }
    }
  }
}

// -------- row softmax: normalize f32 weights in place + emit bf16 copy --------
__global__ __launch_bounds__(256) void softmax_rows(float* __restrict__ w,
                                                    unsigned short* __restrict__ pb) {
  long row = blockIdx.x;
  float* p = w + row * C_LEN;
  unsigned short* pbp = pb + row * C_LEN;
  int t = threadIdx.x;
  int wid = t >> 6;
  f32x4 v[4];
  float mx = -3.4e38f;
#pragma unroll
  for (int j = 0; j < 4; ++j) {
    v[j] = __builtin_nontemporal_load((const f32x4*)(p + j * 1024 + t * 4));
    mx = fmaxf(mx, fmaxf(fmaxf(v[j].x, v[j].y), fmaxf(v[j].z, v[j].w)));
  }
#pragma unroll
  for (int o = 1; o < 64; o <<= 1) mx = fmaxf(mx, __shfl_xor(mx, o));
  __shared__ float redm[4];
  if ((t & 63) == 0) redm[wid] = mx;
  __syncthreads();
  mx = fmaxf(fmaxf(redm[0], redm[1]), fmaxf(redm[2], redm[3]));
  float sum = 0.f;
#pragma unroll
  for (int j = 0; j < 4; ++j) {
    v[j].x = __expf(v[j].x - mx);
    v[j].y = __expf(v[j].y - mx);
    v[j].z = __expf(v[j].z - mx);
    v[j].w = __expf(v[j].w - mx);
    sum += v[j].x + v[j].y + v[j].z + v[j].w;
  }
#pragma unroll
  for (int o = 1; o < 64; o <<= 1) sum += __shfl_xor(sum, o);
  __shared__ float reds[4];
  if ((t & 63) == 0) reds[wid] = sum;
  __syncthreads();
  sum = reds[0] + reds[1] + reds[2] + reds[3];
  float inv = 1.0f / sum;
#pragma unroll
  for (int j = 0; j < 4; ++j) {
    v[j].x *= inv;
    v[j].y *= inv;
    v[j].z *= inv;
    v[j].w *= inv;
    __builtin_nontemporal_store(v[j], (f32x4*)(p + j * 1024 + t * 4));
    u16x4 o16 = {f2bf(v[j].x), f2bf(v[j].y), f2bf(v[j].z), f2bf(v[j].w)};
    *(u16x4*)(pbp + j * 1024 + t * 4) = o16;
  }
}

extern "C" void kernel_launch(void* const* d_in, const int* in_sizes, int n_in,
                              void* d_out, int out_size, void* d_ws, size_t ws_size,
                              hipStream_t stream) {
  const float* x = (const float*)d_in[0];
  const float* mask = (const float*)d_in[1];
  const float* Wq = (const float*)d_in[2];
  const float* Wk = (const float*)d_in[3];
  const float* Wv = (const float*)d_in[4];
  float* out = (float*)d_out;                           // [B][C][E]
  float* weights = out + (long)NBATCH * C_LEN * E_DIM;  // [B][C][C]

  char* ws = (char*)d_ws;
  const bool big = ws_size >= (160ull << 20);
  float* cosT = (float*)(ws);
  float* sinT = (float*)(ws + (8l << 20));
  unsigned short* x_bf = (unsigned short*)(ws + (16l << 20));
  unsigned short* W_bf = (unsigned short*)(ws + (48l << 20));  // [3072][1024] = Q|K|V
  unsigned short* Q_bf = (unsigned short*)(ws + (54l << 20));
  unsigned short* K_bf = (unsigned short*)(ws + (86l << 20));
  unsigned short* Vt = (unsigned short*)(ws + (big ? (128l << 20) : (118l << 20)));
  unsigned short* P_bf = (unsigned short*)(ws);

  dim3 blk(256);
  dim3 blk512(512);

  rope_table<<<dim3((C_LEN * (E_DIM / 2)) / 256), blk, 0, stream>>>(cosT, sinT);
  cvt_all<<<dim3(19456), blk, 0, stream>>>(x, Wq, Wk, Wv, x_bf, W_bf);

  // fused QKV projection: 64 rt x 12 ct = 768 blocks
  gemm8<0><<<dim3(768), blk512, 0, stream>>>(
      x_bf, W_bf, 0, 0, 0, 64, 12, E_DIM, 3 * E_DIM,
      Q_bf, K_bf, Vt, nullptr, cosT, sinT, nullptr);

  // scores = QK^T/32 + mask -> 16 rt x 16 ct x 4 bz = 1024 blocks
  gemm8<2><<<dim3(1024), blk512, 0, stream>>>(
      Q_bf, K_bf, (long)C_LEN * E_DIM, (long)C_LEN * E_DIM, (long)C_LEN * C_LEN,
      16, 16, E_DIM, C_LEN, nullptr, nullptr, nullptr, weights, nullptr, nullptr, mask);

  if (big) {
    softmax_rows<<<dim3(NBATCH * C_LEN), blk, 0, stream>>>(weights, P_bf);
    // out = P @ V: 16 rt x 4 ct x 4 bz = 256 blocks
    gemm8<3><<<dim3(256), blk512, 0, stream>>>(
        P_bf, Vt, (long)C_LEN * C_LEN, (long)E_DIM * C_LEN, (long)C_LEN * E_DIM,
        16, 4, C_LEN, E_DIM, nullptr, nullptr, nullptr, out, nullptr, nullptr, nullptr);
  } else {
    for (int h = 0; h < 2; ++h) {
      float* wgt = weights + (long)h * 2 * C_LEN * C_LEN;
      softmax_rows<<<dim3(2 * C_LEN), blk, 0, stream>>>(wgt, P_bf);
      gemm8<3><<<dim3(128), blk512, 0, stream>>>(
          P_bf, Vt + (long)h * 2 * E_DIM * C_LEN, (long)C_LEN * C_LEN, (long)E_DIM * C_LEN,
          (long)C_LEN * E_DIM, 16, 4, C_LEN, E_DIM,
          nullptr, nullptr, nullptr, out + (long)h * 2 * C_LEN * E_DIM,
          nullptr, nullptr, nullptr);
    }
  }
}